// Round 1
// baseline (476.351 us; speedup 1.0000x reference)
//
#include <hip/hip_runtime.h>
#include <stdint.h>

#define B_   16
#define C_   512
#define H_   64
#define W_   64
#define NH_  8
#define HD_  64
#define HW_  4096

typedef __attribute__((ext_vector_type(8))) _Float16 f16x8;
typedef __attribute__((ext_vector_type(8))) unsigned short u16x8;
typedef __attribute__((ext_vector_type(4))) unsigned short u16x4;
typedef __attribute__((ext_vector_type(4))) float f32x4;

static __device__ __forceinline__ unsigned short f2h(float f) {
  _Float16 h = (_Float16)f;
  unsigned short u;
  __builtin_memcpy(&u, &h, 2);
  return u;
}

static __device__ __forceinline__ void gld_lds16(const void* g, void* l) {
  __builtin_amdgcn_global_load_lds((__attribute__((address_space(1))) void*)g,
                                   (__attribute__((address_space(3))) void*)l,
                                   16, 0, 0);
}

// ---------------- K0a: x (B,C,HW) fp32 -> xT (B,HW,C) f16 (transpose+convert)
__global__ __launch_bounds__(256) void rcca_tr(const float* __restrict__ x,
                                               unsigned short* __restrict__ xT) {
  __shared__ float lT[64 * 65];
  const int bid = blockIdx.x;
  const int st = bid & 63;          // hw tile
  const int ct = (bid >> 6) & 7;    // c tile
  const int b  = bid >> 9;
  const int t = threadIdx.x;
  const int hwl = t & 63;
  const int cl0 = (t >> 6) * 16;
  const float* src = x + ((size_t)(b * C_ + ct * 64 + cl0)) * HW_ + st * 64 + hwl;
#pragma unroll
  for (int jj = 0; jj < 16; ++jj)
    lT[(cl0 + jj) * 65 + hwl] = src[(size_t)jj * HW_];
  __syncthreads();
  const int hw2 = t >> 2;
  const int cc0 = (t & 3) * 16;
  u16x8 o0, o1;
#pragma unroll
  for (int u = 0; u < 8; ++u) {
    o0[u] = f2h(lT[(cc0 + u) * 65 + hw2]);
    o1[u] = f2h(lT[(cc0 + 8 + u) * 65 + hw2]);
  }
  unsigned short* dst = xT + ((size_t)b * HW_ + st * 64 + hw2) * C_ + ct * 64 + cc0;
  *(u16x8*)dst = o0;
  *(u16x8*)(dst + 8) = o1;
}

// ---------------- K0b: wq|wk|wv (512,512) fp32 -> Wc (1536,512) f16
__global__ __launch_bounds__(256) void rcca_cvtw(const float* __restrict__ wq,
                                                 const float* __restrict__ wk,
                                                 const float* __restrict__ wv,
                                                 unsigned short* __restrict__ Wc) {
  const int i = blockIdx.x * 256 + threadIdx.x;  // 196608 threads
  const int e = i * 4;
  const float* w = (e < 262144) ? wq : (e < 524288) ? wk : wv;
  const int off = e & 262143;
  const float4 v = *(const float4*)(w + off);
  u16x4 p;
  p[0] = f2h(v.x); p[1] = f2h(v.y); p[2] = f2h(v.z); p[3] = f2h(v.w);
  *(u16x4*)(Wc + e) = p;
}

// ---------------- K1: QKV projection GEMM. D[m=hw][n=(qkv,head,d)] = sum_c xT[m,c]*W[n,c] + bias
// Output layout: qkv[(sel, b, head, h, w, d)] f16
__global__ __launch_bounds__(256) void rcca_gemm(const unsigned short* __restrict__ xT,
                                                 const unsigned short* __restrict__ Wc,
                                                 const float* __restrict__ bq,
                                                 const float* __restrict__ bk,
                                                 const float* __restrict__ bv,
                                                 unsigned short* __restrict__ qkv) {
  __shared__ unsigned short lA[128 * 64];  // [m][k]
  __shared__ unsigned short lB[128 * 64];  // [n][k]
  const int bid = blockIdx.x;
  const int nt = bid % 12;
  const int mt = (bid / 12) & 31;
  const int b  = bid / (12 * 32);
  const int t = threadIdx.x;
  const int wid = t >> 6, lane = t & 63, r = lane & 15, q = lane >> 4;
  const int wm = wid >> 1, wn = wid & 1;
  const unsigned short* Abase = xT + ((size_t)b * HW_ + mt * 128) * C_;
  const unsigned short* Bbase = Wc + (size_t)nt * 128 * C_;
  const int arow = t >> 3;          // 0..31
  const int acol = (t & 7) * 8;     // ushort offset
  char* lAb = (char*)lA;
  char* lBb = (char*)lB;
  const int wbase = wid * 1024;
  f32x4 acc[4][4];
#pragma unroll
  for (int i = 0; i < 4; ++i)
#pragma unroll
    for (int j = 0; j < 4; ++j)
      acc[i][j] = (f32x4){0.f, 0.f, 0.f, 0.f};

  for (int k0 = 0; k0 < C_; k0 += 64) {
    __syncthreads();
#pragma unroll
    for (int rr = 0; rr < 4; ++rr) {
      gld_lds16(Abase + (size_t)(rr * 32 + arow) * C_ + k0 + acol, lAb + rr * 4096 + wbase);
      gld_lds16(Bbase + (size_t)(rr * 32 + arow) * C_ + k0 + acol, lBb + rr * 4096 + wbase);
    }
    __syncthreads();
#pragma unroll
    for (int kk = 0; kk < 64; kk += 32) {
      f16x8 av[4], bw[4];
#pragma unroll
      for (int i = 0; i < 4; ++i)
        av[i] = *(const f16x8*)&lA[(wm * 64 + i * 16 + r) * 64 + kk + q * 8];
#pragma unroll
      for (int j = 0; j < 4; ++j)
        bw[j] = *(const f16x8*)&lB[(wn * 64 + j * 16 + r) * 64 + kk + q * 8];
#pragma unroll
      for (int i = 0; i < 4; ++i)
#pragma unroll
        for (int j = 0; j < 4; ++j)
          acc[i][j] = __builtin_amdgcn_mfma_f32_16x16x32_f16(av[i], bw[j], acc[i][j], 0, 0, 0);
    }
  }
  // epilogue: C layout col=lane&15, row=quad*4+reg (m89-verified)
  const int headq = nt * 2 + wn;        // 0..23
  const int qsel = headq >> 3;
  const int head = headq & 7;
  const float* bias = (qsel == 0) ? bq : (qsel == 1) ? bk : bv;
  const int h = mt * 2 + wm;
  unsigned short* dst0 = qkv + (size_t)qsel * ((size_t)B_ * NH_ * H_ * W_ * HD_)
                       + (((size_t)b * NH_ + head) * H_ + h) * (size_t)(W_ * HD_);
#pragma unroll
  for (int j = 0; j < 4; ++j) {
    const int d = j * 16 + r;
    const float bias_v = bias[head * 64 + d];
#pragma unroll
    for (int i = 0; i < 4; ++i) {
#pragma unroll
      for (int reg = 0; reg < 4; ++reg) {
        const int w = i * 16 + q * 4 + reg;
        dst0[(size_t)w * HD_ + d] = f2h(acc[i][j][reg] + bias_v);
      }
    }
  }
}

// ---------------- K2: attention per (b, head, h); S=QK^T, softmax, O=PV, +residual
__global__ __launch_bounds__(256) void rcca_attn(const unsigned short* __restrict__ Qb,
                                                 const unsigned short* __restrict__ Kb,
                                                 const unsigned short* __restrict__ Vb,
                                                 const float* __restrict__ x,
                                                 float* __restrict__ out) {
  __shared__ __align__(16) char smem[36864];
  unsigned short* sQ = (unsigned short*)smem;            // [64][72] (w,d)
  unsigned short* sK = (unsigned short*)(smem + 9216);   // [64][72] (w,d)
  unsigned short* sV = (unsigned short*)(smem + 18432);  // [64][72] (d,w)  (transposed)
  unsigned short* sP = (unsigned short*)(smem + 27648);  // [64][72] (w,w')
  float* sO = (float*)smem;                              // [64][66] (d,w) overlays sQ+sK
  const int bid = blockIdx.x;
  const int h = bid & 63, head = (bid >> 6) & 7, b = bid >> 9;
  const size_t base = (((size_t)b * NH_ + head) * H_ + h) * (size_t)(W_ * HD_);
  const int t = threadIdx.x;
  {
    const int w = t >> 2, c0 = (t & 3) * 16;
    const size_t off = base + (size_t)t * 16;
    u16x8 a0 = *(const u16x8*)(Qb + off);
    u16x8 a1 = *(const u16x8*)(Qb + off + 8);
    *(u16x8*)&sQ[w * 72 + c0] = a0;
    *(u16x8*)&sQ[w * 72 + c0 + 8] = a1;
    u16x8 k0v = *(const u16x8*)(Kb + off);
    u16x8 k1v = *(const u16x8*)(Kb + off + 8);
    *(u16x8*)&sK[w * 72 + c0] = k0v;
    *(u16x8*)&sK[w * 72 + c0 + 8] = k1v;
    u16x8 v0 = *(const u16x8*)(Vb + off);
    u16x8 v1 = *(const u16x8*)(Vb + off + 8);
#pragma unroll
    for (int jj = 0; jj < 8; ++jj) {
      sV[(c0 + jj) * 72 + w] = v0[jj];
      sV[(c0 + 8 + jj) * 72 + w] = v1[jj];
    }
  }
  __syncthreads();
  const int wv = t >> 6, lane = t & 63, r = lane & 15, q = lane >> 4;
  f32x4 s[4];
#pragma unroll
  for (int j = 0; j < 4; ++j) s[j] = (f32x4){0.f, 0.f, 0.f, 0.f};
#pragma unroll
  for (int kk = 0; kk < 64; kk += 32) {
    f16x8 aq = *(const f16x8*)&sQ[(wv * 16 + r) * 72 + kk + q * 8];
#pragma unroll
    for (int j = 0; j < 4; ++j) {
      f16x8 bk8 = *(const f16x8*)&sK[(j * 16 + r) * 72 + kk + q * 8];
      s[j] = __builtin_amdgcn_mfma_f32_16x16x32_f16(aq, bk8, s[j], 0, 0, 0);
    }
  }
  // softmax over w' (no scale in reference); lane holds S[row=wv*16+q*4+reg][col=j*16+r]
  float inv[4];
#pragma unroll
  for (int reg = 0; reg < 4; ++reg) {
    float mx = fmaxf(fmaxf(s[0][reg], s[1][reg]), fmaxf(s[2][reg], s[3][reg]));
#pragma unroll
    for (int o = 1; o < 16; o <<= 1) mx = fmaxf(mx, __shfl_xor(mx, o, 64));
    float p0 = __expf(s[0][reg] - mx);
    float p1 = __expf(s[1][reg] - mx);
    float p2 = __expf(s[2][reg] - mx);
    float p3 = __expf(s[3][reg] - mx);
    float sum = p0 + p1 + p2 + p3;
#pragma unroll
    for (int o = 1; o < 16; o <<= 1) sum += __shfl_xor(sum, o, 64);
    inv[reg] = 1.0f / sum;
    const int row = wv * 16 + q * 4 + reg;
    sP[row * 72 + 0 + r]  = f2h(p0);
    sP[row * 72 + 16 + r] = f2h(p1);
    sP[row * 72 + 32 + r] = f2h(p2);
    sP[row * 72 + 48 + r] = f2h(p3);
  }
  __syncthreads();  // all waves done reading sQ/sK before sO overlays them
  f32x4 o4[4];
#pragma unroll
  for (int j = 0; j < 4; ++j) o4[j] = (f32x4){0.f, 0.f, 0.f, 0.f};
#pragma unroll
  for (int kk = 0; kk < 64; kk += 32) {
    f16x8 ap = *(const f16x8*)&sP[(wv * 16 + r) * 72 + kk + q * 8];
#pragma unroll
    for (int jd = 0; jd < 4; ++jd) {
      f16x8 bv8 = *(const f16x8*)&sV[(jd * 16 + r) * 72 + kk + q * 8];
      o4[jd] = __builtin_amdgcn_mfma_f32_16x16x32_f16(ap, bv8, o4[jd], 0, 0, 0);
    }
  }
#pragma unroll
  for (int jd = 0; jd < 4; ++jd) {
    const int d = jd * 16 + r;
#pragma unroll
    for (int reg = 0; reg < 4; ++reg) {
      const int w = wv * 16 + q * 4 + reg;
      sO[d * 66 + w] = o4[jd][reg] * inv[reg];
    }
  }
  __syncthreads();
  // out[b][head*64+d][h][w] = O[w][d] + x[...]; coalesced float4 along w
  const int d = t >> 2, w0 = (t & 3) * 16;
  const size_t obase = ((size_t)b * C_ + head * 64 + d) * HW_ + h * 64 + w0;
  const float4* xr = (const float4*)(x + obase);
  float4* op = (float4*)(out + obase);
#pragma unroll
  for (int u = 0; u < 4; ++u) {
    float4 xv = xr[u];
    float4 ov;
    ov.x = sO[d * 66 + w0 + u * 4 + 0] + xv.x;
    ov.y = sO[d * 66 + w0 + u * 4 + 1] + xv.y;
    ov.z = sO[d * 66 + w0 + u * 4 + 2] + xv.z;
    ov.w = sO[d * 66 + w0 + u * 4 + 3] + xv.w;
    op[u] = ov;
  }
}

extern "C" void kernel_launch(void* const* d_in, const int* in_sizes, int n_in,
                              void* d_out, int out_size, void* d_ws, size_t ws_size,
                              hipStream_t stream) {
  const float* x  = (const float*)d_in[0];
  const float* wq = (const float*)d_in[1];
  const float* bq = (const float*)d_in[2];
  const float* wk = (const float*)d_in[3];
  const float* bk = (const float*)d_in[4];
  const float* wv = (const float*)d_in[5];
  const float* bv = (const float*)d_in[6];
  float* out = (float*)d_out;
  char* ws = (char*)d_ws;
  // ws layout: xT 64 MiB | Wc 1.5 MiB | QKV 3x64 MiB  (total ~258 MiB)
  unsigned short* xT = (unsigned short*)ws;
  unsigned short* Wc = (unsigned short*)(ws + (size_t)67108864);
  unsigned short* Qb = (unsigned short*)(ws + (size_t)68681728);
  unsigned short* Kb = Qb + (size_t)33554432;
  unsigned short* Vb = Kb + (size_t)33554432;
  hipLaunchKernelGGL(rcca_tr,   dim3(8192), dim3(256), 0, stream, x, xT);
  hipLaunchKernelGGL(rcca_cvtw, dim3(768),  dim3(256), 0, stream, wq, wk, wv, Wc);
  hipLaunchKernelGGL(rcca_gemm, dim3(6144), dim3(256), 0, stream, xT, Wc, bq, bk, bv, Qb);
  hipLaunchKernelGGL(rcca_attn, dim3(8192), dim3(256), 0, stream, Qb, Kb, Vb, x, out);
}

// Round 2
// 474.303 us; speedup vs baseline: 1.0043x; 1.0043x over previous
//
#include <hip/hip_runtime.h>
#include <stdint.h>

#define B_   16
#define C_   512
#define H_   64
#define W_   64
#define NH_  8
#define HD_  64
#define HW_  4096

typedef __attribute__((ext_vector_type(8))) _Float16 f16x8;
typedef __attribute__((ext_vector_type(8))) unsigned short u16x8;
typedef __attribute__((ext_vector_type(4))) unsigned short u16x4;
typedef __attribute__((ext_vector_type(4))) float f32x4;

static __device__ __forceinline__ unsigned short f2h(float f) {
  _Float16 h = (_Float16)f;
  unsigned short u;
  __builtin_memcpy(&u, &h, 2);
  return u;
}

static __device__ __forceinline__ void gld_lds16(const void* g, void* l) {
  __builtin_amdgcn_global_load_lds((__attribute__((address_space(1))) void*)g,
                                   (__attribute__((address_space(3))) void*)l,
                                   16, 0, 0);
}

// ---------------- K0a: x (B,C,HW) fp32 -> xT (B,HW,C) f16 (transpose+convert)
__global__ __launch_bounds__(256) void rcca_tr(const float* __restrict__ x,
                                               unsigned short* __restrict__ xT) {
  __shared__ float lT[64 * 65];
  const int bid = blockIdx.x;
  const int st = bid & 63;          // hw tile
  const int ct = (bid >> 6) & 7;    // c tile
  const int b  = bid >> 9;
  const int t = threadIdx.x;
  const int hwl = t & 63;
  const int cl0 = (t >> 6) * 16;
  const float* src = x + ((size_t)(b * C_ + ct * 64 + cl0)) * HW_ + st * 64 + hwl;
#pragma unroll
  for (int jj = 0; jj < 16; ++jj)
    lT[(cl0 + jj) * 65 + hwl] = src[(size_t)jj * HW_];
  __syncthreads();
  const int hw2 = t >> 2;
  const int cc0 = (t & 3) * 16;
  u16x8 o0, o1;
#pragma unroll
  for (int u = 0; u < 8; ++u) {
    o0[u] = f2h(lT[(cc0 + u) * 65 + hw2]);
    o1[u] = f2h(lT[(cc0 + 8 + u) * 65 + hw2]);
  }
  unsigned short* dst = xT + ((size_t)b * HW_ + st * 64 + hw2) * C_ + ct * 64 + cc0;
  *(u16x8*)dst = o0;
  *(u16x8*)(dst + 8) = o1;
}

// ---------------- K0b: wq|wk|wv (512,512) fp32 -> Wc (1536,512) f16
__global__ __launch_bounds__(256) void rcca_cvtw(const float* __restrict__ wq,
                                                 const float* __restrict__ wk,
                                                 const float* __restrict__ wv,
                                                 unsigned short* __restrict__ Wc) {
  const int i = blockIdx.x * 256 + threadIdx.x;  // 196608 threads
  const int e = i * 4;
  const float* w = (e < 262144) ? wq : (e < 524288) ? wk : wv;
  const int off = e & 262143;
  const float4 v = *(const float4*)(w + off);
  u16x4 p;
  p[0] = f2h(v.x); p[1] = f2h(v.y); p[2] = f2h(v.z); p[3] = f2h(v.w);
  *(u16x4*)(Wc + e) = p;
}

// ---------------- K1: QKV projection GEMM. D[m=hw][n=(qkv,head,d)] = sum_c xT[m,c]*W[n,c] + bias
// LDS tiles use XOR chunk-swizzle: LDS(row, chunk) holds global(row, chunk ^ (row&7));
// fragment reads address chunk ((q + kk/8) ^ (r&7)) -> conflict-free b128.
// Output layout: qkv[(sel, b, head, h, w, d)] f16
__global__ __launch_bounds__(256) void rcca_gemm(const unsigned short* __restrict__ xT,
                                                 const unsigned short* __restrict__ Wc,
                                                 const float* __restrict__ bq,
                                                 const float* __restrict__ bk,
                                                 const float* __restrict__ bv,
                                                 unsigned short* __restrict__ qkv) {
  __shared__ __align__(16) char gsm[34816];
  unsigned short* lA = (unsigned short*)gsm;            // [128][64] swizzled
  unsigned short* lB = (unsigned short*)(gsm + 16384);  // [128][64] swizzled
  unsigned short* sT = (unsigned short*)gsm;            // [128][136] epilogue C-tile
  const int bid = blockIdx.x;
  const int nt = bid % 12;
  const int mt = (bid / 12) & 31;
  const int b  = bid / (12 * 32);
  const int t = threadIdx.x;
  const int wid = t >> 6, lane = t & 63, r = lane & 15, q = lane >> 4;
  const int rx = r & 7;
  const int wm = wid >> 1, wn = wid & 1;
  const unsigned short* Abase = xT + ((size_t)b * HW_ + mt * 128) * C_;
  const unsigned short* Bbase = Wc + (size_t)nt * 128 * C_;
  const int arow = t >> 3;                               // 0..31
  const int acol = (((t & 7) ^ ((t >> 3) & 7)) * 8);     // swizzled ushort col
  char* lAb = (char*)lA;
  char* lBb = (char*)lB;
  const int wbase = wid * 1024;
  f32x4 acc[4][4];
#pragma unroll
  for (int i = 0; i < 4; ++i)
#pragma unroll
    for (int j = 0; j < 4; ++j)
      acc[i][j] = (f32x4){0.f, 0.f, 0.f, 0.f};

  for (int k0 = 0; k0 < C_; k0 += 64) {
    __syncthreads();
#pragma unroll
    for (int rr = 0; rr < 4; ++rr) {
      gld_lds16(Abase + (size_t)(rr * 32 + arow) * C_ + k0 + acol, lAb + rr * 4096 + wbase);
      gld_lds16(Bbase + (size_t)(rr * 32 + arow) * C_ + k0 + acol, lBb + rr * 4096 + wbase);
    }
    __syncthreads();
#pragma unroll
    for (int kk = 0; kk < 64; kk += 32) {
      const int cbase = kk >> 3;  // 0 or 4
      f16x8 av[4], bw[4];
#pragma unroll
      for (int i = 0; i < 4; ++i)
        av[i] = *(const f16x8*)&lA[(wm * 64 + i * 16 + r) * 64 + (((cbase + q) ^ rx) * 8)];
#pragma unroll
      for (int j = 0; j < 4; ++j)
        bw[j] = *(const f16x8*)&lB[(wn * 64 + j * 16 + r) * 64 + (((cbase + q) ^ rx) * 8)];
#pragma unroll
      for (int i = 0; i < 4; ++i)
#pragma unroll
        for (int j = 0; j < 4; ++j)
          acc[i][j] = __builtin_amdgcn_mfma_f32_16x16x32_f16(av[i], bw[j], acc[i][j], 0, 0, 0);
    }
  }
  // ---- epilogue via LDS transpose: acc (C layout col=lane&15, row=quad*4+reg) -> sT[m][n]
  __syncthreads();
  const int headq = nt * 2 + wn;        // 0..23
  const int qsel = headq >> 3;
  const int head = headq & 7;
  const float* bias = (qsel == 0) ? bq : (qsel == 1) ? bk : bv;
#pragma unroll
  for (int j = 0; j < 4; ++j) {
    const float bias_v = bias[head * 64 + j * 16 + r];
#pragma unroll
    for (int i = 0; i < 4; ++i) {
#pragma unroll
      for (int reg = 0; reg < 4; ++reg) {
        const int m = wm * 64 + i * 16 + q * 4 + reg;
        const int n = wn * 64 + j * 16 + r;
        sT[m * 136 + n] = f2h(acc[i][j][reg] + bias_v);
      }
    }
  }
  __syncthreads();
  // coalesced u16x8 stores: thread t covers row wr = t>>1, n-half = t&1
  const int wr = t >> 1, half = t & 1;
  const int hq2 = nt * 2 + half;
  const int qs2 = hq2 >> 3;
  const int hd2 = hq2 & 7;
  const int h2 = mt * 2 + (wr >> 6);
  const int w2 = wr & 63;
  unsigned short* dstb = qkv + (size_t)qs2 * ((size_t)B_ * NH_ * H_ * W_ * HD_)
                       + (((size_t)b * NH_ + hd2) * H_ + h2) * (size_t)(W_ * HD_)
                       + (size_t)w2 * HD_;
#pragma unroll
  for (int u = 0; u < 8; ++u)
    *(u16x8*)(dstb + u * 8) = *(const u16x8*)&sT[wr * 136 + half * 64 + u * 8];
}

// ---------------- K2: attention per (b, head, h); S=QK^T, softmax, O=PV, +residual
__global__ __launch_bounds__(256) void rcca_attn(const unsigned short* __restrict__ Qb,
                                                 const unsigned short* __restrict__ Kb,
                                                 const unsigned short* __restrict__ Vb,
                                                 const float* __restrict__ x,
                                                 float* __restrict__ out) {
  __shared__ __align__(16) char smem[36864];
  unsigned short* sQ = (unsigned short*)smem;            // [64][72] (w,d)
  unsigned short* sK = (unsigned short*)(smem + 9216);   // [64][72] (w,d)
  unsigned short* sV = (unsigned short*)(smem + 18432);  // [64][72] (d,w)  (transposed)
  unsigned short* sP = (unsigned short*)(smem + 27648);  // [64][72] (w,w')
  float* sO = (float*)smem;                              // [64][66] (d,w) overlays sQ+sK
  const int bid = blockIdx.x;
  const int h = bid & 63, head = (bid >> 6) & 7, b = bid >> 9;
  const size_t base = (((size_t)b * NH_ + head) * H_ + h) * (size_t)(W_ * HD_);
  const int t = threadIdx.x;
  {
    const int w = t >> 2, c0 = (t & 3) * 16;
    const size_t off = base + (size_t)t * 16;
    u16x8 a0 = *(const u16x8*)(Qb + off);
    u16x8 a1 = *(const u16x8*)(Qb + off + 8);
    *(u16x8*)&sQ[w * 72 + c0] = a0;
    *(u16x8*)&sQ[w * 72 + c0 + 8] = a1;
    u16x8 k0v = *(const u16x8*)(Kb + off);
    u16x8 k1v = *(const u16x8*)(Kb + off + 8);
    *(u16x8*)&sK[w * 72 + c0] = k0v;
    *(u16x8*)&sK[w * 72 + c0 + 8] = k1v;
    // V with w-major lane mapping: 64 distinct w per wave -> 2-way (free) sV writes
    const int wv2 = t & 63, cv0 = (t >> 6) * 16;
    const size_t voff = base + (size_t)wv2 * HD_ + cv0;
    u16x8 v0 = *(const u16x8*)(Vb + voff);
    u16x8 v1 = *(const u16x8*)(Vb + voff + 8);
#pragma unroll
    for (int jj = 0; jj < 8; ++jj) {
      sV[(cv0 + jj) * 72 + wv2] = v0[jj];
      sV[(cv0 + 8 + jj) * 72 + wv2] = v1[jj];
    }
  }
  __syncthreads();
  const int wv = t >> 6, lane = t & 63, r = lane & 15, q = lane >> 4;
  f32x4 s[4];
#pragma unroll
  for (int j = 0; j < 4; ++j) s[j] = (f32x4){0.f, 0.f, 0.f, 0.f};
#pragma unroll
  for (int kk = 0; kk < 64; kk += 32) {
    f16x8 aq = *(const f16x8*)&sQ[(wv * 16 + r) * 72 + kk + q * 8];
#pragma unroll
    for (int j = 0; j < 4; ++j) {
      f16x8 bk8 = *(const f16x8*)&sK[(j * 16 + r) * 72 + kk + q * 8];
      s[j] = __builtin_amdgcn_mfma_f32_16x16x32_f16(aq, bk8, s[j], 0, 0, 0);
    }
  }
  // softmax over w' (no scale in reference); lane holds S[row=wv*16+q*4+reg][col=j*16+r]
  float inv[4];
#pragma unroll
  for (int reg = 0; reg < 4; ++reg) {
    float mx = fmaxf(fmaxf(s[0][reg], s[1][reg]), fmaxf(s[2][reg], s[3][reg]));
#pragma unroll
    for (int o = 1; o < 16; o <<= 1) mx = fmaxf(mx, __shfl_xor(mx, o, 64));
    float p0 = __expf(s[0][reg] - mx);
    float p1 = __expf(s[1][reg] - mx);
    float p2 = __expf(s[2][reg] - mx);
    float p3 = __expf(s[3][reg] - mx);
    float sum = p0 + p1 + p2 + p3;
#pragma unroll
    for (int o = 1; o < 16; o <<= 1) sum += __shfl_xor(sum, o, 64);
    inv[reg] = 1.0f / sum;
    const int row = wv * 16 + q * 4 + reg;
    sP[row * 72 + 0 + r]  = f2h(p0);
    sP[row * 72 + 16 + r] = f2h(p1);
    sP[row * 72 + 32 + r] = f2h(p2);
    sP[row * 72 + 48 + r] = f2h(p3);
  }
  __syncthreads();  // all waves done reading sQ/sK before sO overlays them
  f32x4 o4[4];
#pragma unroll
  for (int j = 0; j < 4; ++j) o4[j] = (f32x4){0.f, 0.f, 0.f, 0.f};
#pragma unroll
  for (int kk = 0; kk < 64; kk += 32) {
    f16x8 ap = *(const f16x8*)&sP[(wv * 16 + r) * 72 + kk + q * 8];
#pragma unroll
    for (int jd = 0; jd < 4; ++jd) {
      f16x8 bv8 = *(const f16x8*)&sV[(jd * 16 + r) * 72 + kk + q * 8];
      o4[jd] = __builtin_amdgcn_mfma_f32_16x16x32_f16(ap, bv8, o4[jd], 0, 0, 0);
    }
  }
#pragma unroll
  for (int jd = 0; jd < 4; ++jd) {
    const int d = jd * 16 + r;
#pragma unroll
    for (int reg = 0; reg < 4; ++reg) {
      const int w = wv * 16 + q * 4 + reg;
      sO[d * 66 + w] = o4[jd][reg] * inv[reg];
    }
  }
  __syncthreads();
  // out[b][head*64+d][h][w] = O[w][d] + x[...]; coalesced float4 along w
  const int d = t >> 2, w0 = (t & 3) * 16;
  const size_t obase = ((size_t)b * C_ + head * 64 + d) * HW_ + h * 64 + w0;
  const float4* xr = (const float4*)(x + obase);
  float4* op = (float4*)(out + obase);
#pragma unroll
  for (int u = 0; u < 4; ++u) {
    float4 xv = xr[u];
    float4 ov;
    ov.x = sO[d * 66 + w0 + u * 4 + 0] + xv.x;
    ov.y = sO[d * 66 + w0 + u * 4 + 1] + xv.y;
    ov.z = sO[d * 66 + w0 + u * 4 + 2] + xv.z;
    ov.w = sO[d * 66 + w0 + u * 4 + 3] + xv.w;
    op[u] = ov;
  }
}

extern "C" void kernel_launch(void* const* d_in, const int* in_sizes, int n_in,
                              void* d_out, int out_size, void* d_ws, size_t ws_size,
                              hipStream_t stream) {
  const float* x  = (const float*)d_in[0];
  const float* wq = (const float*)d_in[1];
  const float* bq = (const float*)d_in[2];
  const float* wk = (const float*)d_in[3];
  const float* bk = (const float*)d_in[4];
  const float* wv = (const float*)d_in[5];
  const float* bv = (const float*)d_in[6];
  float* out = (float*)d_out;
  char* ws = (char*)d_ws;
  // ws layout: xT 64 MiB | Wc 1.5 MiB | QKV 3x64 MiB  (total ~258 MiB)
  unsigned short* xT = (unsigned short*)ws;
  unsigned short* Wc = (unsigned short*)(ws + (size_t)67108864);
  unsigned short* Qb = (unsigned short*)(ws + (size_t)68681728);
  unsigned short* Kb = Qb + (size_t)33554432;
  unsigned short* Vb = Kb + (size_t)33554432;
  hipLaunchKernelGGL(rcca_tr,   dim3(8192), dim3(256), 0, stream, x, xT);
  hipLaunchKernelGGL(rcca_cvtw, dim3(768),  dim3(256), 0, stream, wq, wk, wv, Wc);
  hipLaunchKernelGGL(rcca_gemm, dim3(6144), dim3(256), 0, stream, xT, Wc, bq, bk, bv, Qb);
  hipLaunchKernelGGL(rcca_attn, dim3(8192), dim3(256), 0, stream, Qb, Kb, Vb, x, out);
}